// Round 1
// baseline (42.692 us; speedup 1.0000x reference)
//
#include <hip/hip_runtime.h>

// Problem constants (16 x 8 x 512 x 512 fp32, 2x2 grey opening + MSE)
#define IMG_H 512
#define IMG_W 512
#define NIMG 128               // 16 * 8
#define ROWCHUNK 32
#define NCHUNK (IMG_H / ROWCHUNK)   // 16
#define NCG (IMG_W / 4)             // 128 column-groups of 4
#define THREADS 256
#define TOTAL_THREADS (NIMG * NCHUNK * NCG)   // 262144
#define NBLOCKS (TOTAL_THREADS / THREADS)     // 1024

__global__ __launch_bounds__(THREADS)
void opening_mse_kernel(const float* __restrict__ X, float* __restrict__ out) {
    const int t = blockIdx.x * THREADS + threadIdx.x;
    const int cg    = t & (NCG - 1);          // column group  (consecutive lanes -> coalesced)
    const int chunk = (t >> 7) & (NCHUNK - 1);
    const int n     = t >> 11;                // image index

    const int c0 = cg * 4;
    const float* __restrict__ img = X + (size_t)n * IMG_H * IMG_W;

    const int cl = (c0 > 0) ? (c0 - 1) : 0;           // left halo col (clamped)
    const int cr = (c0 + 4 < IMG_W) ? (c0 + 4) : (IMG_W - 1); // right halo col (clamped)

    // Load one row: 4 owned values + horizontal pairwise mins h[k] = min(x[c-1], x[c])
    // for the 5 columns c0..c0+4 (h[4] belongs to col c0+4, needed for hd of col c0+3).
    auto loadrow = [&](int r, float4& x4, float (&h)[5]) {
        const float* __restrict__ row = img + (size_t)r * IMG_W;
        x4 = *reinterpret_cast<const float4*>(row + c0);
        const float xl = row[cl];
        const float xr = row[cr];
        h[0] = fminf(xl, x4.x);
        h[1] = fminf(x4.x, x4.y);
        h[2] = fminf(x4.y, x4.z);
        h[3] = fminf(x4.z, x4.w);
        h[4] = fminf(x4.w, xr);
    };

    const int s = chunk * ROWCHUNK;
    const int e = s + ROWCHUNK;   // compute opened rows [s, e)

    float4 xprev;
    float  hprev[5], hcur[5];
    float  hdprev[4], hdcur[4];

    // Prime: h at row s-1 (clamped to 0), h at row s, hd[s].
    {
        float4 dummy;
        loadrow((s > 0) ? (s - 1) : 0, dummy, hprev);
        loadrow(s, xprev, hcur);
        float E[5];
        #pragma unroll
        for (int k = 0; k < 5; ++k) E[k] = fminf(hprev[k], hcur[k]);
        #pragma unroll
        for (int k = 0; k < 4; ++k) hdprev[k] = fmaxf(E[k], E[k + 1]);
        #pragma unroll
        for (int k = 0; k < 5; ++k) hprev[k] = hcur[k];
    }

    float acc = 0.0f;
    float4 xs;

    for (int a = s + 1; a <= e; ++a) {
        if (a < IMG_H) {
            loadrow(a, xs, hcur);
            float E[5];
            #pragma unroll
            for (int k = 0; k < 5; ++k) E[k] = fminf(hprev[k], hcur[k]);
            #pragma unroll
            for (int k = 0; k < 4; ++k) hdcur[k] = fmaxf(E[k], E[k + 1]);
        } else {
            // hd[H] clamps to hd[H-1]
            #pragma unroll
            for (int k = 0; k < 4; ++k) hdcur[k] = hdprev[k];
        }
        // opened row a-1 = max(hd[a-1], hd[a]); MSE term vs x row a-1
        float o0 = fmaxf(hdprev[0], hdcur[0]);
        float o1 = fmaxf(hdprev[1], hdcur[1]);
        float o2 = fmaxf(hdprev[2], hdcur[2]);
        float o3 = fmaxf(hdprev[3], hdcur[3]);
        float d0 = xprev.x - o0;
        float d1 = xprev.y - o1;
        float d2 = xprev.z - o2;
        float d3 = xprev.w - o3;
        acc = fmaf(d0, d0, acc);
        acc = fmaf(d1, d1, acc);
        acc = fmaf(d2, d2, acc);
        acc = fmaf(d3, d3, acc);

        #pragma unroll
        for (int k = 0; k < 4; ++k) hdprev[k] = hdcur[k];
        #pragma unroll
        for (int k = 0; k < 5; ++k) hprev[k] = hcur[k];
        xprev = xs;
    }

    // ---- reduction: wave shuffle -> LDS across 4 waves -> one atomic per block
    const int lane = threadIdx.x & 63;
    const int wid  = threadIdx.x >> 6;
    #pragma unroll
    for (int off = 32; off > 0; off >>= 1)
        acc += __shfl_down(acc, off, 64);

    __shared__ float wsum[THREADS / 64];
    if (lane == 0) wsum[wid] = acc;
    __syncthreads();
    if (threadIdx.x == 0) {
        float sblk = wsum[0] + wsum[1] + wsum[2] + wsum[3];
        // divide by N = 2^25 (exact scale) so atomics accumulate the mean directly
        atomicAdd(out, sblk * (1.0f / 33554432.0f));
    }
}

extern "C" void kernel_launch(void* const* d_in, const int* in_sizes, int n_in,
                              void* d_out, int out_size, void* d_ws, size_t ws_size,
                              hipStream_t stream) {
    const float* X = (const float*)d_in[0];
    float* out = (float*)d_out;
    hipMemsetAsync(out, 0, sizeof(float), stream);
    opening_mse_kernel<<<NBLOCKS, THREADS, 0, stream>>>(X, out);
}

// Round 2
// 35.449 us; speedup vs baseline: 1.2043x; 1.2043x over previous
//
#include <hip/hip_runtime.h>

// 16 x 8 x 512 x 512 fp32; 2x2 grey opening + MSE (scalar out)
#define IMG_H 512
#define IMG_W 512
#define NIMG 128
#define CHUNK 32
#define NCHUNK (IMG_H / CHUNK)      // 16
#define THREADS 256
#define WPB (THREADS / 64)          // 4 waves / block
#define NBLOCKS (NIMG * NCHUNK / WPB)   // 512

__global__ __launch_bounds__(THREADS)
void opening_mse_kernel(const float* __restrict__ X, float* __restrict__ out) {
    const int lane = threadIdx.x & 63;
    const int gw   = blockIdx.x * WPB + (threadIdx.x >> 6);
    const int n     = gw >> 4;              // image 0..127
    const int chunk = gw & (NCHUNK - 1);    // 0..15
    const int s = chunk * CHUNK;
    const int e = s + CHUNK;                // output rows [s, e)
    const float* __restrict__ img = X + (size_t)n * (IMG_H * IMG_W);
    const int cb = lane << 3;               // 8 cols per lane; wave spans 512 cols

    auto ld = [&](int r, float4& a, float4& b) {
        const float* __restrict__ p = img + (size_t)r * IMG_W + cb;
        a = *reinterpret_cast<const float4*>(p);
        b = *reinterpret_cast<const float4*>(p + 4);
    };

    // h[k] = min(x[c-1], x[c]) for c = cb+k, k=0..8 (h[8] is virtual col for dilation).
    // Left halo via shuffle (lane 0 clamps); lane 63: h[8]=h[7] implements the
    // dilation reflect-pad (opened[.,511] window = eroded col 511 twice).
    auto mkh = [&](const float4& a, const float4& b, float (&h)[9]) {
        float xl = __shfl_up(b.w, 1, 64);
        if (lane == 0) xl = a.x;
        float xr = __shfl_down(a.x, 1, 64);
        h[0] = fminf(xl, a.x);
        h[1] = fminf(a.x, a.y);
        h[2] = fminf(a.y, a.z);
        h[3] = fminf(a.z, a.w);
        h[4] = fminf(a.w, b.x);
        h[5] = fminf(b.x, b.y);
        h[6] = fminf(b.y, b.z);
        h[7] = fminf(b.z, b.w);
        h[8] = (lane == 63) ? h[7] : fminf(b.w, xr);
    };

    float hprev[9], hd[8];
    float4 xa, xb;   // x of the row whose opened value we emit next (row a-1)

    {   // prime: h(row s-1 clamped), h(row s), hd[s]
        float4 ta, tb;
        ld(s > 0 ? s - 1 : 0, ta, tb);
        mkh(ta, tb, hprev);
        ld(s, xa, xb);
        float hcur[9], E[9];
        mkh(xa, xb, hcur);
        #pragma unroll
        for (int k = 0; k < 9; ++k) E[k] = fminf(hprev[k], hcur[k]);
        #pragma unroll
        for (int k = 0; k < 8; ++k) hd[k] = fmaxf(E[k], E[k + 1]);
        #pragma unroll
        for (int k = 0; k < 9; ++k) hprev[k] = hcur[k];
    }

    // 2-deep row prefetch (s+1, s+2 always exist: s <= 480)
    float4 a1, b1, a2, b2;
    ld(s + 1, a1, b1);
    ld(s + 2, a2, b2);

    float acc = 0.0f;
    #pragma unroll 2
    for (int a = s + 1; a <= e; ++a) {
        float4 ca = a1, cbv = b1;
        a1 = a2; b1 = b2;
        if (a + 2 <= e && a + 2 < IMG_H) ld(a + 2, a2, b2);

        float hdc[8];
        if (a < IMG_H) {
            float hcur[9], E[9];
            mkh(ca, cbv, hcur);
            #pragma unroll
            for (int k = 0; k < 9; ++k) E[k] = fminf(hprev[k], hcur[k]);
            #pragma unroll
            for (int k = 0; k < 8; ++k) hdc[k] = fmaxf(E[k], E[k + 1]);
            #pragma unroll
            for (int k = 0; k < 9; ++k) hprev[k] = hcur[k];
        } else {
            #pragma unroll
            for (int k = 0; k < 8; ++k) hdc[k] = hd[k];   // hd[H] := hd[H-1]
        }

        // opened row a-1 = max(hd[a-1], hd[a]); accumulate squared error vs x
        float d;
        d = xa.x - fmaxf(hd[0], hdc[0]); acc = fmaf(d, d, acc);
        d = xa.y - fmaxf(hd[1], hdc[1]); acc = fmaf(d, d, acc);
        d = xa.z - fmaxf(hd[2], hdc[2]); acc = fmaf(d, d, acc);
        d = xa.w - fmaxf(hd[3], hdc[3]); acc = fmaf(d, d, acc);
        d = xb.x - fmaxf(hd[4], hdc[4]); acc = fmaf(d, d, acc);
        d = xb.y - fmaxf(hd[5], hdc[5]); acc = fmaf(d, d, acc);
        d = xb.z - fmaxf(hd[6], hdc[6]); acc = fmaf(d, d, acc);
        d = xb.w - fmaxf(hd[7], hdc[7]); acc = fmaf(d, d, acc);

        #pragma unroll
        for (int k = 0; k < 8; ++k) hd[k] = hdc[k];
        xa = ca; xb = cbv;
    }

    // wave shuffle reduce -> LDS across 4 waves -> one atomic per block
    #pragma unroll
    for (int off = 32; off > 0; off >>= 1)
        acc += __shfl_down(acc, off, 64);

    __shared__ float wsum[WPB];
    const int wid = threadIdx.x >> 6;
    if (lane == 0) wsum[wid] = acc;
    __syncthreads();
    if (threadIdx.x == 0) {
        float sblk = wsum[0] + wsum[1] + wsum[2] + wsum[3];
        atomicAdd(out, sblk * (1.0f / 33554432.0f));   // / 2^25 -> mean
    }
}

extern "C" void kernel_launch(void* const* d_in, const int* in_sizes, int n_in,
                              void* d_out, int out_size, void* d_ws, size_t ws_size,
                              hipStream_t stream) {
    const float* X = (const float*)d_in[0];
    float* out = (float*)d_out;
    hipMemsetAsync(out, 0, sizeof(float), stream);
    opening_mse_kernel<<<NBLOCKS, THREADS, 0, stream>>>(X, out);
}